// Round 19
// baseline (198.151 us; speedup 1.0000x reference)
//
#include <hip/hip_runtime.h>
#include <hip/hip_bf16.h>

// ---------------------------------------------------------------------------
// AlsoDecoder, folded + fp16 MFMA, CUSTOM-FP4 S-table + HIGH OCCUPANCY:
//   S4[p] = q4( feats[p]@W_f - pcd[p]@W_p + b_in )   (32B/row, L2-RESIDENT:
//           3.2MB < 4MB/XCD; R18 proved FETCH is compulsory-only)
//   nibble decode fp16 = ((em<<9)+0x3800)|s<<15 -> +/-{.5,.75,1,1.5,2,3,4,6}*scl
//   x1 = S4[col]*scl + also_pts[row]@W_p
//   y  = relu(x1) @ W1 ; h2 = relu(y+b1) ; probs = sigmoid(h2.wdiff + bfd)
// R14/R17 occupancy failures were L2 capacity-thrash; with the table L2-fit
// that mechanism is absent, so 6 waves/SIMD (LDS constants, 384-fix staging)
// now attacks the exposed ~200cyc L2-hit latency with no traffic penalty.
// ---------------------------------------------------------------------------

typedef _Float16 half8 __attribute__((ext_vector_type(8)));
typedef _Float16 half2v __attribute__((ext_vector_type(2)));
typedef __fp16   fp16x2 __attribute__((ext_vector_type(2)));
typedef __attribute__((ext_vector_type(4))) float f32x4;
typedef __attribute__((ext_vector_type(2))) float f32x2;

#define FP4_SCL 0.39f
#define FP4_INV 2.5641026f

union UPH  { half2v h; fp16x2 f; int i; unsigned u; };
union H8U  { half8 h; half2v p[4]; };

__device__ __forceinline__ half2v cvt2h(float a, float b) {
    UPH t;
    t.f = __builtin_amdgcn_cvt_pkrtz(a, b);
    return t.h;
}

// decode one byte (2 fp4 codes: low nibble = elem0) -> half2 (unscaled units)
__device__ __forceinline__ half2v fp4pair(unsigned b) {
    unsigned u = (b & 0xFu) | ((b & 0xF0u) << 12);
    unsigned em2 = u & 0x00070007u;
    unsigned s2  = (u & 0x00080008u) << 12;
    UPH t;
    t.u = ((em2 << 9) + 0x38003800u) | s2;
    return t.h;
}

__device__ __forceinline__ half8 relu8(half8 v) {
    half8 z;
#pragma unroll
    for (int i = 0; i < 8; ++i) z[i] = (_Float16)0.f;
    return __builtin_elementwise_max(v, z);
}
__device__ __forceinline__ half8 splat8h(_Float16 h) {
    half8 r = {h, h, h, h, h, h, h, h};
    return r;
}

// ---------------- prep: pack weights (verbatim from passed rounds) ---------
__global__ __launch_bounds__(256) void pack_fold(
    const float* __restrict__ w1, const float* __restrict__ w_in,
    const float* __restrict__ b1, const float* __restrict__ w2,
    const float* __restrict__ w_out, const float* __restrict__ b2,
    const float* __restrict__ b_out,
    _Float16* __restrict__ w1f, _Float16* __restrict__ wAf,
    _Float16* __restrict__ wpf, _Float16* __restrict__ wdh,
    _Float16* __restrict__ b1h, float* __restrict__ bfd) {
    int t = blockIdx.x * 256 + threadIdx.x;
    if (t < 4096) {
        int f = t >> 9, lane = (t >> 3) & 63, j = t & 7;
        int ntile = f >> 1, kstep = f & 1;
        int k = kstep * 32 + ((lane >> 4) << 3) + j;
        int n = ntile * 16 + (lane & 15);
        w1f[t] = (_Float16)w1[k * 64 + n];
    } else if (t < 10240) {
        int i = t - 4096;
        int f = i >> 9, lane = (i >> 3) & 63, j = i & 7;
        int ntile = f / 3, ks = f % 3;
        int n = ntile * 16 + (lane & 15);
        float v;
        if (ks < 2) {
            int k = ks * 32 + ((lane >> 4) << 3) + j;
            v = w_in[k * 64 + n];
        } else {
            v = ((lane >> 4) == 0 && j < 3) ? -w_in[(64 + j) * 64 + n] : 0.f;
        }
        wAf[i] = (_Float16)v;
    } else if (t < 13312) {
        int i = t - 10240;                      // d*1024 + ks*512 + lane*8 + j
        int d = i >> 10, ks = (i >> 9) & 1, lane = (i >> 3) & 63, j = i & 7;
        int k = ks * 32 + ((lane >> 4) << 3) + j;
        wpf[i] = (_Float16)w_in[(64 + d) * 64 + k];
    } else if (t < 13376) {
        int n = t - 13312;
        float s = 0.f;
#pragma unroll
        for (int j = 0; j < 64; ++j)
            s = fmaf(w2[n * 64 + j], w_out[j * 2 + 0] - w_out[j * 2 + 1], s);
        wdh[n] = (_Float16)s;
    } else if (t < 13440) {
        int n = t - 13376;
        b1h[n] = (_Float16)b1[n];
    } else if (t == 13440) {
        float s = b_out[0] - b_out[1];
#pragma unroll
        for (int j = 0; j < 64; ++j)
            s = fmaf(b2[j], w_out[j * 2 + 0] - w_out[j * 2 + 1], s);
        bfd[0] = s;
    }
}

// ---------------- prep: S table via MFMA, fp4-packed (verbatim R18) --------
__global__ __launch_bounds__(256) void precompute_S(
    const float* __restrict__ feats, const float* __restrict__ pcd,
    const float* __restrict__ b_in, const half8* __restrict__ wAf,
    unsigned char* __restrict__ S4, int N) {
    int lane = threadIdx.x & 63;
    int idx = lane & 15, g = lane >> 4;
    int base16 = (blockIdx.x * 4 + (threadIdx.x >> 6)) * 16;
    if (base16 >= N) return;

    half8 wa[12];
#pragma unroll
    for (int f = 0; f < 12; ++f) wa[f] = wAf[f * 64 + lane];

    int p = base16 + idx;
    int ps = p < N ? p : N - 1;
    const float4* fp = (const float4*)(feats + (size_t)ps * 64);
    float4 f0 = fp[2 * g], f1 = fp[2 * g + 1];
    float4 f2 = fp[8 + 2 * g], f3 = fp[8 + 2 * g + 1];
    half8 b0, b1v, b2v;
    b0[0]=(_Float16)f0.x; b0[1]=(_Float16)f0.y; b0[2]=(_Float16)f0.z; b0[3]=(_Float16)f0.w;
    b0[4]=(_Float16)f1.x; b0[5]=(_Float16)f1.y; b0[6]=(_Float16)f1.z; b0[7]=(_Float16)f1.w;
    b1v[0]=(_Float16)f2.x; b1v[1]=(_Float16)f2.y; b1v[2]=(_Float16)f2.z; b1v[3]=(_Float16)f2.w;
    b1v[4]=(_Float16)f3.x; b1v[5]=(_Float16)f3.y; b1v[6]=(_Float16)f3.z; b1v[7]=(_Float16)f3.w;
    float px = 0.f, py = 0.f, pz = 0.f;
    if (g == 0) {
        const float* pp = pcd + (size_t)ps * 3;
        px = pp[0]; py = pp[1]; pz = pp[2];
    }
#pragma unroll
    for (int i = 0; i < 8; ++i) b2v[i] = (_Float16)0.f;
    b2v[0] = (_Float16)px; b2v[1] = (_Float16)py; b2v[2] = (_Float16)pz;

#pragma unroll
    for (int tt = 0; tt < 4; ++tt) {
        f32x4 bi = *(const f32x4*)(b_in + tt * 16 + 4 * g);
        f32x4 acc;
        acc = __builtin_amdgcn_mfma_f32_16x16x32_f16(wa[tt * 3 + 0], b0, bi, 0, 0, 0);
        acc = __builtin_amdgcn_mfma_f32_16x16x32_f16(wa[tt * 3 + 1], b1v, acc, 0, 0, 0);
        acc = __builtin_amdgcn_mfma_f32_16x16x32_f16(wa[tt * 3 + 2], b2v, acc, 0, 0, 0);
        unsigned pk = 0;
#pragma unroll
        for (int rr = 0; rr < 4; ++rr) {
            float v = acc[rr] * FP4_INV;
            unsigned s = (v < 0.f) ? 8u : 0u;
            float y = fabsf(v);
            unsigned em = (unsigned)((y > 0.625f) + (y > 0.875f) + (y > 1.25f)
                        + (y > 1.75f) + (y > 2.5f) + (y > 3.5f) + (y > 5.f));
            pk |= (s | em) << (4 * rr);
        }
        int base = ((2 * (tt & 1) + (g >> 1)) << 3) + ((tt >> 1) << 2) + ((g & 1) << 1);
        if (p < N)
            *(unsigned short*)(S4 + (size_t)p * 32 + base) = (unsigned short)pk;
    }
}

// ---------------- edge kernel (LDS constants, 6 waves/SIMD) ----------------
__global__ __launch_bounds__(256, 6) void edge_mfma(
    const unsigned char* __restrict__ S4, const float* __restrict__ also_pts,
    const int* __restrict__ row, const int* __restrict__ col,
    const int* __restrict__ labels,
    const half8* __restrict__ w1f, const half8* __restrict__ wpf,
    const unsigned* __restrict__ wdp, const unsigned* __restrict__ b1p,
    const float* __restrict__ bfdp,
    float* __restrict__ out, int E, int ngroups) {
    __shared__ half8 wf_lds[8][64];     // W1 A-frags (512 half8)
    __shared__ half8 wpd_lds[6][64];    // W_p B-frags (384 half8)
    __shared__ unsigned wd_lds[32];     // packed fp16 pairs of wdiff
    __shared__ unsigned b1_lds[32];     // packed fp16 pairs of b1
    {
        int t = threadIdx.x;
        ((half8*)wf_lds)[t] = w1f[t];
        ((half8*)wf_lds)[t + 256] = w1f[t + 256];
        ((half8*)wpd_lds)[t] = wpf[t];                          // 0..255
        if (t < 128) ((half8*)wpd_lds)[t + 256] = wpf[t + 256]; // 256..383
        if (t < 32) { wd_lds[t] = wdp[t]; b1_lds[t] = b1p[t]; }
    }
    __syncthreads();

    int lane = threadIdx.x & 63;
    int idx  = lane & 15;          // edge-in-group (D col)
    int g    = lane >> 4;
    float bfd = bfdp[0];
    half2v zero2 = {(_Float16)0.f, (_Float16)0.f};
    half8 scl8 = splat8h((_Float16)FP4_SCL);

    int gwave  = blockIdx.x * 4 + (threadIdx.x >> 6);
    int nwaves = gridDim.x * 4;

    for (int grp = gwave; grp < ngroups; grp += nwaves) {
        int e = (grp << 4) + idx;
        bool eok = e < E;
        int es = eok ? e : E - 1;
        int r = __builtin_nontemporal_load(row + es);
        int c = __builtin_nontemporal_load(col + es);

        // single 8B fp4 gather = both fragments of this lane (L2-resident)
        uint2 sv = *(const uint2*)(S4 + (size_t)c * 32 + g * 8);
        const float* ap = also_pts + (size_t)r * 3;
        float ax = ap[0], ay = ap[1], az = ap[2];
        int lb = labels[r];

        // decode 16 fp4 -> f16 (units); scale folds into pk_fma below
        H8U s0u, s1u;
        s0u.p[0] = fp4pair(sv.x & 0xFFu);
        s0u.p[1] = fp4pair((sv.x >> 8) & 0xFFu);
        s0u.p[2] = fp4pair((sv.x >> 16) & 0xFFu);
        s0u.p[3] = fp4pair(sv.x >> 24);
        s1u.p[0] = fp4pair(sv.y & 0xFFu);
        s1u.p[1] = fp4pair((sv.y >> 8) & 0xFFu);
        s1u.p[2] = fp4pair((sv.y >> 16) & 0xFFu);
        s1u.p[3] = fp4pair(sv.y >> 24);

        // Q rebuild from W_p frags (LDS); x = relu(S*scl + Q)
        half8 av = splat8h((_Float16)ax);
        half8 bv = splat8h((_Float16)ay);
        half8 cv = splat8h((_Float16)az);
        half8 q0 = av * wpd_lds[0][lane] + bv * wpd_lds[2][lane] + cv * wpd_lds[4][lane];
        half8 q1 = av * wpd_lds[1][lane] + bv * wpd_lds[3][lane] + cv * wpd_lds[5][lane];
        half8 x0 = relu8(s0u.h * scl8 + q0);
        half8 x1 = relu8(s1u.h * scl8 + q1);

        // Y = W1'.X : lane holds Y[n=tt*16+4g+rr][edge=idx]
        f32x4 zero = {0.f, 0.f, 0.f, 0.f};
        f32x4 acc[4];
#pragma unroll
        for (int tt = 0; tt < 4; ++tt) {
            acc[tt] = __builtin_amdgcn_mfma_f32_16x16x32_f16(wf_lds[2 * tt][lane],     x0, zero, 0, 0, 0);
            acc[tt] = __builtin_amdgcn_mfma_f32_16x16x32_f16(wf_lds[2 * tt + 1][lane], x1, acc[tt], 0, 0, 0);
        }

        // packed fold: h2 = relu(y + b1); pd += h2 * wdiff
        half2v pd = zero2;
#pragma unroll
        for (int tt = 0; tt < 4; ++tt) {
            UPH b0u, b1u, w0u, w1u;
            int i0 = tt * 8 + 2 * g;
            b0u.u = b1_lds[i0];     b1u.u = b1_lds[i0 + 1];
            w0u.u = wd_lds[i0];     w1u.u = wd_lds[i0 + 1];
            half2v h01 = cvt2h(acc[tt][0], acc[tt][1]);
            half2v h23 = cvt2h(acc[tt][2], acc[tt][3]);
            h01 = __builtin_elementwise_max(h01 + b0u.h, zero2);
            h23 = __builtin_elementwise_max(h23 + b1u.h, zero2);
            pd += h01 * w0u.h + h23 * w1u.h;
        }
        UPH P, T;
        P.h = pd;
        T.i = __shfl_xor(P.i, 16); P.h += T.h;
        T.i = __shfl_xor(P.i, 32); P.h += T.h;

        if (g == 0 && eok) {
            float l = (float)P.h[0] + (float)P.h[1];
            float u = __expf(-(l + bfd));
            float pa = 1.f / (1.f + u);
            f32x2 pr = {pa, 1.f - pa};
            __builtin_nontemporal_store(pr, (f32x2*)(out + (size_t)e * 2));
            __builtin_nontemporal_store((float)lb, out + (size_t)2 * E + e);
        }
    }
}

extern "C" void kernel_launch(void* const* d_in, const int* in_sizes, int n_in,
                              void* d_out, int out_size, void* d_ws, size_t ws_size,
                              hipStream_t stream) {
    const float* pcd      = (const float*)d_in[0];
    const float* feats    = (const float*)d_in[1];
    const float* also_pts = (const float*)d_in[2];
    const int*   labels   = (const int*)d_in[3];
    const int*   row      = (const int*)d_in[4];
    const int*   col      = (const int*)d_in[5];
    const float* w_in     = (const float*)d_in[6];
    const float* b_in     = (const float*)d_in[7];
    const float* w1       = (const float*)d_in[8];
    const float* b1       = (const float*)d_in[9];
    const float* w2       = (const float*)d_in[10];
    const float* b2       = (const float*)d_in[11];
    const float* w_out    = (const float*)d_in[12];
    const float* b_out    = (const float*)d_in[13];

    int N = in_sizes[0] / 3;
    int E = in_sizes[4];

    unsigned char* S4 = (unsigned char*)d_ws;                 // N*32 bytes
    _Float16* w1f = (_Float16*)(S4 + (size_t)N * 32);
    _Float16* wAf = w1f + 4096;
    _Float16* wpf = wAf + 6144;
    _Float16* wdh = wpf + 3072;
    _Float16* b1h = wdh + 64;
    float*    bfd = (float*)(b1h + 64);

    pack_fold<<<53, 256, 0, stream>>>(w1, w_in, b1, w2, w_out, b2, b_out,
                                      w1f, wAf, wpf, wdh, b1h, bfd);

    int ngroupsS = (N + 15) / 16;
    precompute_S<<<(ngroupsS + 3) / 4, 256, 0, stream>>>(
        feats, pcd, b_in, (const half8*)wAf, S4, N);

    int ngroups = (E + 15) / 16;
    edge_mfma<<<1536, 256, 0, stream>>>(S4, also_pts, row, col, labels,
                                        (const half8*)w1f, (const half8*)wpf,
                                        (const unsigned*)wdh, (const unsigned*)b1h,
                                        bfd, (float*)d_out, E, ngroups);
}

// Round 20
// 77.680 us; speedup vs baseline: 2.5509x; 2.5509x over previous
//
#include <hip/hip_runtime.h>
#include <hip/hip_bf16.h>

// ---------------------------------------------------------------------------
// AlsoDecoder FINAL (revert to R15 best-known), folded + fp16 MFMA, fp8 table:
//   S8[p] = fp8_e4m3( feats[p]@W_f - pcd[p]@W_p + b_in )   (64B/row, packed
//           in per-lane fragment byte order; one 16B load/lane)
//   x1 = S8[col] (fp8->f16) + also_pts[row]@W_p
//   y  = relu(x1) @ W1               (mfma 16x16x32 f16, swapped operands)
//   h2 = relu(y + b1);  ldiff = h2 . wdiff ;  probs = sigmoid(ldiff + bfd)
// Session map (evidence): occupancy 37%->63% explodes FETCH 3-6x at ANY
// table size (R14/R17/R19); ILP levers null/negative (R8/R10); sort-by-col
// pays 7.8x write amplification (R11); nt hints null (R16); fp4 decode VALU
// exceeds traffic saving at low occ (R18). fp8 + 37% occ is the optimum.
// ---------------------------------------------------------------------------

typedef _Float16 half8 __attribute__((ext_vector_type(8)));
typedef _Float16 half2v __attribute__((ext_vector_type(2)));
typedef __fp16   fp16x2 __attribute__((ext_vector_type(2)));
typedef __attribute__((ext_vector_type(4))) float f32x4;

union UPH  { half2v h; fp16x2 f; int i; unsigned u; };
union H8U  { half8 h; half2v p[4]; };

__device__ __forceinline__ half2v cvt2h(float a, float b) {
    UPH t;
    t.f = __builtin_amdgcn_cvt_pkrtz(a, b);
    return t.h;
}
__device__ __forceinline__ half2v fp8lo(unsigned d) {
    auto f = __builtin_amdgcn_cvt_pk_f32_fp8((int)d, false);
    return cvt2h(f[0], f[1]);
}
__device__ __forceinline__ half2v fp8hi(unsigned d) {
    auto f = __builtin_amdgcn_cvt_pk_f32_fp8((int)d, true);
    return cvt2h(f[0], f[1]);
}

__device__ __forceinline__ half8 relu8(half8 v) {
    half8 z;
#pragma unroll
    for (int i = 0; i < 8; ++i) z[i] = (_Float16)0.f;
    return __builtin_elementwise_max(v, z);
}
__device__ __forceinline__ half8 splat8h(_Float16 h) {
    half8 r = {h, h, h, h, h, h, h, h};
    return r;
}

// ---------------- prep: pack weights --------------------------------------
__global__ __launch_bounds__(256) void pack_fold(
    const float* __restrict__ w1, const float* __restrict__ w_in,
    const float* __restrict__ b1, const float* __restrict__ w2,
    const float* __restrict__ w_out, const float* __restrict__ b2,
    const float* __restrict__ b_out,
    _Float16* __restrict__ w1f, _Float16* __restrict__ wAf,
    _Float16* __restrict__ wpf, _Float16* __restrict__ wdh,
    _Float16* __restrict__ b1h, float* __restrict__ bfd) {
    int t = blockIdx.x * 256 + threadIdx.x;
    if (t < 4096) {
        int f = t >> 9, lane = (t >> 3) & 63, j = t & 7;
        int ntile = f >> 1, kstep = f & 1;
        int k = kstep * 32 + ((lane >> 4) << 3) + j;
        int n = ntile * 16 + (lane & 15);
        w1f[t] = (_Float16)w1[k * 64 + n];
    } else if (t < 10240) {
        int i = t - 4096;
        int f = i >> 9, lane = (i >> 3) & 63, j = i & 7;
        int ntile = f / 3, ks = f % 3;
        int n = ntile * 16 + (lane & 15);
        float v;
        if (ks < 2) {
            int k = ks * 32 + ((lane >> 4) << 3) + j;
            v = w_in[k * 64 + n];
        } else {
            v = ((lane >> 4) == 0 && j < 3) ? -w_in[(64 + j) * 64 + n] : 0.f;
        }
        wAf[i] = (_Float16)v;
    } else if (t < 13312) {
        int i = t - 10240;                      // d*1024 + ks*512 + lane*8 + j
        int d = i >> 10, ks = (i >> 9) & 1, lane = (i >> 3) & 63, j = i & 7;
        int k = ks * 32 + ((lane >> 4) << 3) + j;
        wpf[i] = (_Float16)w_in[(64 + d) * 64 + k];
    } else if (t < 13376) {
        int n = t - 13312;
        float s = 0.f;
#pragma unroll
        for (int j = 0; j < 64; ++j)
            s = fmaf(w2[n * 64 + j], w_out[j * 2 + 0] - w_out[j * 2 + 1], s);
        wdh[n] = (_Float16)s;
    } else if (t < 13440) {
        int n = t - 13376;
        b1h[n] = (_Float16)b1[n];
    } else if (t == 13440) {
        float s = b_out[0] - b_out[1];
#pragma unroll
        for (int j = 0; j < 64; ++j)
            s = fmaf(b2[j], w_out[j * 2 + 0] - w_out[j * 2 + 1], s);
        bfd[0] = s;
    }
}

// ---------------- prep: S table via MFMA, fp8-packed output ----------------
__global__ __launch_bounds__(256) void precompute_S(
    const float* __restrict__ feats, const float* __restrict__ pcd,
    const float* __restrict__ b_in, const half8* __restrict__ wAf,
    unsigned char* __restrict__ S8, int N) {
    int lane = threadIdx.x & 63;
    int idx = lane & 15, g = lane >> 4;
    int base16 = (blockIdx.x * 4 + (threadIdx.x >> 6)) * 16;
    if (base16 >= N) return;

    half8 wa[12];
#pragma unroll
    for (int f = 0; f < 12; ++f) wa[f] = wAf[f * 64 + lane];

    int p = base16 + idx;
    int ps = p < N ? p : N - 1;
    const float4* fp = (const float4*)(feats + (size_t)ps * 64);
    float4 f0 = fp[2 * g], f1 = fp[2 * g + 1];
    float4 f2 = fp[8 + 2 * g], f3 = fp[8 + 2 * g + 1];
    half8 b0, b1v, b2v;
    b0[0]=(_Float16)f0.x; b0[1]=(_Float16)f0.y; b0[2]=(_Float16)f0.z; b0[3]=(_Float16)f0.w;
    b0[4]=(_Float16)f1.x; b0[5]=(_Float16)f1.y; b0[6]=(_Float16)f1.z; b0[7]=(_Float16)f1.w;
    b1v[0]=(_Float16)f2.x; b1v[1]=(_Float16)f2.y; b1v[2]=(_Float16)f2.z; b1v[3]=(_Float16)f2.w;
    b1v[4]=(_Float16)f3.x; b1v[5]=(_Float16)f3.y; b1v[6]=(_Float16)f3.z; b1v[7]=(_Float16)f3.w;
    float px = 0.f, py = 0.f, pz = 0.f;
    if (g == 0) {
        const float* pp = pcd + (size_t)ps * 3;
        px = pp[0]; py = pp[1]; pz = pp[2];
    }
#pragma unroll
    for (int i = 0; i < 8; ++i) b2v[i] = (_Float16)0.f;
    b2v[0] = (_Float16)px; b2v[1] = (_Float16)py; b2v[2] = (_Float16)pz;

#pragma unroll
    for (int tt = 0; tt < 4; ++tt) {
        f32x4 bi = *(const f32x4*)(b_in + tt * 16 + 4 * g);
        f32x4 acc;
        acc = __builtin_amdgcn_mfma_f32_16x16x32_f16(wa[tt * 3 + 0], b0, bi, 0, 0, 0);
        acc = __builtin_amdgcn_mfma_f32_16x16x32_f16(wa[tt * 3 + 1], b1v, acc, 0, 0, 0);
        acc = __builtin_amdgcn_mfma_f32_16x16x32_f16(wa[tt * 3 + 2], b2v, acc, 0, 0, 0);
        int u = __builtin_amdgcn_cvt_pk_fp8_f32(acc[0], acc[1], 0, false);
        u = __builtin_amdgcn_cvt_pk_fp8_f32(acc[2], acc[3], u, true);
        int nb = tt * 16 + 4 * g;
        int ks = nb >> 5, m = nb & 31;
        int byte_off = ((m >> 3) << 4) + (ks << 3) + (m & 7);
        if (p < N) *(int*)(S8 + (size_t)p * 64 + byte_off) = u;
    }
}

// ---------------- edge kernel --------------------------------------------
__global__ __launch_bounds__(256, 4) void edge_mfma(
    const unsigned char* __restrict__ S8, const float* __restrict__ also_pts,
    const int* __restrict__ row, const int* __restrict__ col,
    const int* __restrict__ labels,
    const half8* __restrict__ w1f, const half8* __restrict__ wpf,
    const unsigned* __restrict__ wdp, const unsigned* __restrict__ b1p,
    const float* __restrict__ bfdp,
    float* __restrict__ out, int E, int ngroups) {
    __shared__ half8 wf_lds[8][64];
    {
        int t = threadIdx.x;
        ((half8*)wf_lds)[t] = w1f[t];
        ((half8*)wf_lds)[t + 256] = w1f[t + 256];
    }
    __syncthreads();

    int lane = threadIdx.x & 63;
    int idx  = lane & 15;          // edge-in-group (D col)
    int g    = lane >> 4;
    int gwave  = blockIdx.x * 4 + (threadIdx.x >> 6);
    int nwaves = gridDim.x * 4;

    half8 wpd[3][2];
#pragma unroll
    for (int d = 0; d < 3; ++d)
#pragma unroll
        for (int ks = 0; ks < 2; ++ks) wpd[d][ks] = wpf[(d * 2 + ks) * 64 + lane];
    UPH wdv[8], b1v[8];
#pragma unroll
    for (int tt = 0; tt < 4; ++tt)
#pragma unroll
        for (int h = 0; h < 2; ++h) {
            int i = tt * 8 + 2 * g + h;
            wdv[tt * 2 + h].u = wdp[i];
            b1v[tt * 2 + h].u = b1p[i];
        }
    float bfd = bfdp[0];
    half2v zero2 = {(_Float16)0.f, (_Float16)0.f};

    for (int grp = gwave; grp < ngroups; grp += nwaves) {
        int e = (grp << 4) + idx;
        bool eok = e < E;
        int es = eok ? e : E - 1;
        int r = row[es], c = col[es];

        // single 16B fp8 gather = both fragments of this lane
        uint4 sv = *(const uint4*)(S8 + (size_t)c * 64 + g * 16);
        const float* ap = also_pts + (size_t)r * 3;
        float ax = ap[0], ay = ap[1], az = ap[2];
        int lb = labels[r];

        H8U s0u, s1u;
        s0u.p[0] = fp8lo(sv.x); s0u.p[1] = fp8hi(sv.x);
        s0u.p[2] = fp8lo(sv.y); s0u.p[3] = fp8hi(sv.y);
        s1u.p[0] = fp8lo(sv.z); s1u.p[1] = fp8hi(sv.z);
        s1u.p[2] = fp8lo(sv.w); s1u.p[3] = fp8hi(sv.w);

        half8 av = splat8h((_Float16)ax);
        half8 bv = splat8h((_Float16)ay);
        half8 cv = splat8h((_Float16)az);
        half8 q0 = av * wpd[0][0] + bv * wpd[1][0] + cv * wpd[2][0];
        half8 q1 = av * wpd[0][1] + bv * wpd[1][1] + cv * wpd[2][1];
        half8 x0 = relu8(s0u.h + q0);
        half8 x1 = relu8(s1u.h + q1);

        f32x4 zero = {0.f, 0.f, 0.f, 0.f};
        f32x4 acc[4];
#pragma unroll
        for (int tt = 0; tt < 4; ++tt) {
            acc[tt] = __builtin_amdgcn_mfma_f32_16x16x32_f16(wf_lds[2 * tt][lane],     x0, zero, 0, 0, 0);
            acc[tt] = __builtin_amdgcn_mfma_f32_16x16x32_f16(wf_lds[2 * tt + 1][lane], x1, acc[tt], 0, 0, 0);
        }

        half2v pd = zero2;
#pragma unroll
        for (int tt = 0; tt < 4; ++tt) {
            half2v h01 = cvt2h(acc[tt][0], acc[tt][1]);
            half2v h23 = cvt2h(acc[tt][2], acc[tt][3]);
            h01 = __builtin_elementwise_max(h01 + b1v[tt * 2 + 0].h, zero2);
            h23 = __builtin_elementwise_max(h23 + b1v[tt * 2 + 1].h, zero2);
            pd += h01 * wdv[tt * 2 + 0].h + h23 * wdv[tt * 2 + 1].h;
        }
        UPH P, T;
        P.h = pd;
        T.i = __shfl_xor(P.i, 16); P.h += T.h;
        T.i = __shfl_xor(P.i, 32); P.h += T.h;

        if (g == 0 && eok) {
            float l = (float)P.h[0] + (float)P.h[1];
            float u = __expf(-(l + bfd));
            float pa = 1.f / (1.f + u);
            *(float2*)(out + (size_t)e * 2) = make_float2(pa, 1.f - pa);
            out[(size_t)2 * E + e] = (float)lb;
        }
    }
}

extern "C" void kernel_launch(void* const* d_in, const int* in_sizes, int n_in,
                              void* d_out, int out_size, void* d_ws, size_t ws_size,
                              hipStream_t stream) {
    const float* pcd      = (const float*)d_in[0];
    const float* feats    = (const float*)d_in[1];
    const float* also_pts = (const float*)d_in[2];
    const int*   labels   = (const int*)d_in[3];
    const int*   row      = (const int*)d_in[4];
    const int*   col      = (const int*)d_in[5];
    const float* w_in     = (const float*)d_in[6];
    const float* b_in     = (const float*)d_in[7];
    const float* w1       = (const float*)d_in[8];
    const float* b1       = (const float*)d_in[9];
    const float* w2       = (const float*)d_in[10];
    const float* b2       = (const float*)d_in[11];
    const float* w_out    = (const float*)d_in[12];
    const float* b_out    = (const float*)d_in[13];

    int N = in_sizes[0] / 3;
    int E = in_sizes[4];

    unsigned char* S8 = (unsigned char*)d_ws;                 // N*64 bytes
    _Float16* w1f = (_Float16*)(S8 + (size_t)N * 64);
    _Float16* wAf = w1f + 4096;
    _Float16* wpf = wAf + 6144;
    _Float16* wdh = wpf + 3072;
    _Float16* b1h = wdh + 64;
    float*    bfd = (float*)(b1h + 64);

    pack_fold<<<53, 256, 0, stream>>>(w1, w_in, b1, w2, w_out, b2, b_out,
                                      w1f, wAf, wpf, wdh, b1h, bfd);

    int ngroupsS = (N + 15) / 16;
    precompute_S<<<(ngroupsS + 3) / 4, 256, 0, stream>>>(
        feats, pcd, b_in, (const half8*)wAf, S8, N);

    int ngroups = (E + 15) / 16;
    edge_mfma<<<2048, 256, 0, stream>>>(S8, also_pts, row, col, labels,
                                        (const half8*)w1f, (const half8*)wpf,
                                        (const unsigned*)wdh, (const unsigned*)b1h,
                                        bfd, (float*)d_out, E, ngroups);
}